// Round 2
// baseline (237.184 us; speedup 1.0000x reference)
//
#include <hip/hip_runtime.h>
#include <hip/hip_bf16.h>

// Problem constants: M=100000 points, K=27 offsets, Cin=Cout=64.
#define NPTS 100000
#define KOFF 27
#define KPAD 28          // padded K: tile 27 is all-zero weight + zero-row gather
#define NCH  64

typedef __attribute__((ext_vector_type(8))) short bf16x8;   // 8 bf16 in 4 VGPRs
typedef __attribute__((ext_vector_type(8))) unsigned short u16x8;
typedef __attribute__((ext_vector_type(4))) float f32x4;

static __device__ __forceinline__ unsigned short f2bf(float x) {
  union { float f; unsigned int u; } v; v.f = x;
  unsigned int r = v.u + 0x7fffu + ((v.u >> 16) & 1u);   // RTNE
  return (unsigned short)(r >> 16);
}

// feats fp32 (M x 64) -> bf16 (M+1 x 64); row NPTS is all-zero (gather target
// for invalid rulebook entries). 8 elements / thread, 16B stores.
__global__ void convert_feats_kernel(const float* __restrict__ feats,
                                     unsigned short* __restrict__ fb) {
  size_t tid  = (size_t)blockIdx.x * blockDim.x + threadIdx.x;
  size_t base = tid * 8;
  const size_t valid_total = (size_t)NPTS * NCH;      // 6,400,000 (divisible by 8)
  const size_t total       = valid_total + NCH;       // + zero row
  if (base >= total) return;
  u16x8 r;
  if (base < valid_total) {
    const float4 a = *reinterpret_cast<const float4*>(feats + base);
    const float4 b = *reinterpret_cast<const float4*>(feats + base + 4);
    r[0] = f2bf(a.x); r[1] = f2bf(a.y); r[2] = f2bf(a.z); r[3] = f2bf(a.w);
    r[4] = f2bf(b.x); r[5] = f2bf(b.y); r[6] = f2bf(b.z); r[7] = f2bf(b.w);
  } else {
    #pragma unroll
    for (int j = 0; j < 8; ++j) r[j] = 0;
  }
  *reinterpret_cast<u16x8*>(fb + base) = r;
}

// weight fp32 [k][cin][cout] -> bf16 [k][cout][cin], 28 tiles (tile 27 = zeros).
__global__ void convert_weight_kernel(const float* __restrict__ w,
                                      unsigned short* __restrict__ wt) {
  int tid = blockIdx.x * 256 + threadIdx.x;
  if (tid >= KPAD * NCH * NCH) return;
  int ko  = tid >> 12;        // /4096
  unsigned short val = 0;
  if (ko < KOFF) {
    int rem = tid & 4095;
    int o   = rem >> 6;
    int c   = rem & 63;
    val = f2bf(w[(size_t)ko * 4096 + c * 64 + o]);
  }
  wt[tid] = val;
}

// Main kernel: block = 64 output rows x 64 cout, 4 waves, wave w owns rows
// [w*16, w*16+16). Depth-4 register pipeline on the A-gathers.
// MFMA 16x16x32 bf16 layouts:
//   A[i][k]: i = lane&15, k = 8*(lane>>4)+j ; B[k][n]: n = lane&15, same k
//   D[i][n]: n = lane&15, i = 4*(lane>>4)+reg
__global__ __launch_bounds__(256)
void spconv_kernel(const unsigned short* __restrict__ fb,      // (NPTS+1) x 64 bf16
                   const int* __restrict__ rulebook,           // NPTS x 27 int32
                   const unsigned short* __restrict__ wt,      // 28 x 64 x 64 bf16 [k][o][c]
                   const float* __restrict__ feats,            // NPTS x 64 fp32 (residual)
                   const float* __restrict__ bias,             // 64 fp32
                   float* __restrict__ out) {                  // NPTS x 64 fp32
  __shared__ int s_off[64][KPAD];    // BYTE offsets into fb (idx*128)
  __shared__ int s_cnt[64];

  const int tid = threadIdx.x;
  const int m0  = blockIdx.x * 64;

  if (tid < 64) s_cnt[tid] = 0;
  __syncthreads();

  // Stage rulebook as byte offsets (invalid / pad-k / OOB row -> zero row).
  for (int f = tid; f < 64 * KPAD; f += 256) {
    int r = f / KPAD, k = f - r * KPAD;
    int m = m0 + r;
    int off = NPTS * 128;
    if (m < NPTS && k < KOFF) {
      int v = rulebook[(size_t)m * KOFF + k];
      if (v >= 0) { off = v * 128; atomicAdd(&s_cnt[r], 1); }
    }
    s_off[r][k] = off;
  }
  __syncthreads();

  const int wave = tid >> 6;
  const int lane = tid & 63;
  const int lr   = lane & 15;      // A-row / B-col / D-col within 16
  const int lk   = lane >> 4;      // k-subgroup
  const int coff = lk * 8;         // element offset within a 32-wide cin chunk
  const int coff_b = lk * 16;      // same, in bytes
  const int row_local = wave * 16 + lr;

  const char* fbase = (const char*)fb;

  f32x4 acc[4] = {f32x4{0,0,0,0}, f32x4{0,0,0,0}, f32x4{0,0,0,0}, f32x4{0,0,0,0}};

  bf16x8 a0_0, a1_0, a0_1, a1_1, a0_2, a1_2, a0_3, a1_3;

#define GATHER(A0, A1, KO) {                                                  \
    const char* p_ = fbase + (size_t)(unsigned)s_off[row_local][(KO)];        \
    A0 = *reinterpret_cast<const bf16x8*>(p_ + coff_b);                       \
    A1 = *reinterpret_cast<const bf16x8*>(p_ + 64 + coff_b);                  \
  }

#define COMPUTE(A0, A1, KO) {                                                 \
    const unsigned short* wko_ = wt + (size_t)(KO) * (NCH * NCH);             \
    _Pragma("unroll")                                                         \
    for (int nt = 0; nt < 4; ++nt) {                                          \
      const unsigned short* wrow_ = wko_ + (nt * 16 + lr) * NCH;              \
      const bf16x8 b0_ = *reinterpret_cast<const bf16x8*>(wrow_ + coff);      \
      const bf16x8 b1_ = *reinterpret_cast<const bf16x8*>(wrow_ + 32 + coff); \
      acc[nt] = __builtin_amdgcn_mfma_f32_16x16x32_bf16(A0, b0_, acc[nt],0,0,0);\
      acc[nt] = __builtin_amdgcn_mfma_f32_16x16x32_bf16(A1, b1_, acc[nt],0,0,0);\
    }                                                                         \
  }

  // Pipeline prologue: 4 gathers in flight.
  GATHER(a0_0, a1_0, 0)
  GATHER(a0_1, a1_1, 1)
  GATHER(a0_2, a1_2, 2)
  GATHER(a0_3, a1_3, 3)

  #pragma unroll 1
  for (int kb = 0; kb < KPAD / 4; ++kb) {
    const int ko = kb * 4;
    COMPUTE(a0_0, a1_0, ko)
    if (ko + 4 < KPAD) GATHER(a0_0, a1_0, ko + 4)
    COMPUTE(a0_1, a1_1, ko + 1)
    if (ko + 5 < KPAD) GATHER(a0_1, a1_1, ko + 5)
    COMPUTE(a0_2, a1_2, ko + 2)
    if (ko + 6 < KPAD) GATHER(a0_2, a1_2, ko + 6)
    COMPUTE(a0_3, a1_3, ko + 3)
    if (ko + 7 < KPAD) GATHER(a0_3, a1_3, ko + 7)
  }
#undef GATHER
#undef COMPUTE

  // Epilogue: /denom + bias + residual, fp32.
  const int orow = wave * 16 + lk * 4;
  #pragma unroll
  for (int nt = 0; nt < 4; ++nt) {
    const int col = nt * 16 + lr;
    const float b = bias[col];
    #pragma unroll
    for (int i = 0; i < 4; ++i) {
      const int rl = orow + i;
      const int m  = m0 + rl;
      if (m < NPTS) {
        const float denom = (float)max(s_cnt[rl], 1);
        out[(size_t)m * NCH + col] =
            acc[nt][i] / denom + b + feats[(size_t)m * NCH + col];
      }
    }
  }
}

extern "C" void kernel_launch(void* const* d_in, const int* in_sizes, int n_in,
                              void* d_out, int out_size, void* d_ws, size_t ws_size,
                              hipStream_t stream) {
  const float* feats    = (const float*)d_in[0];
  const int*   rulebook = (const int*)d_in[1];
  const float* weight   = (const float*)d_in[2];
  const float* bias     = (const float*)d_in[3];
  float* out = (float*)d_out;

  // Workspace layout: [0, ~12.8MB) feats bf16 (M+1 rows); then weight bf16 (28 tiles).
  unsigned short* fb = (unsigned short*)d_ws;
  const size_t fb_bytes = (size_t)(NPTS + 1) * NCH * sizeof(unsigned short); // 12,800,128
  const size_t wt_off   = (fb_bytes + 255) & ~(size_t)255;
  unsigned short* wt = (unsigned short*)((char*)d_ws + wt_off);

  {
    const size_t total = (size_t)(NPTS + 1) * NCH;        // bf16 elements
    const int threads = (int)((total + 7) / 8);
    convert_feats_kernel<<<(threads + 255) / 256, 256, 0, stream>>>(feats, fb);
  }
  {
    const int n = KPAD * NCH * NCH;
    convert_weight_kernel<<<(n + 255) / 256, 256, 0, stream>>>(weight, wt);
  }
  {
    const int nblk = (NPTS + 63) / 64;   // 1563
    spconv_kernel<<<nblk, 256, 0, stream>>>(fb, rulebook, wt, feats, bias, out);
  }
}

// Round 3
// 110.056 us; speedup vs baseline: 2.1551x; 2.1551x over previous
//
#include <hip/hip_runtime.h>
#include <hip/hip_bf16.h>

// Problem constants: M=100000 points, K=27 offsets, Cin=Cout=64.
#define NPTS 100000
#define KOFF 27
#define KPAD 28          // padded K: tile 27 = zero weights + zero-row gathers
#define NCH  64

typedef __attribute__((ext_vector_type(8))) short bf16x8;   // 8 bf16 in 4 VGPRs
typedef __attribute__((ext_vector_type(8))) unsigned short u16x8;
typedef __attribute__((ext_vector_type(4))) float f32x4;

static __device__ __forceinline__ unsigned short f2bf(float x) {
  union { float f; unsigned int u; } v; v.f = x;
  unsigned int r = v.u + 0x7fffu + ((v.u >> 16) & 1u);   // RTNE
  return (unsigned short)(r >> 16);
}

// feats fp32 (M x 64) -> bf16 (M+1 x 64); row NPTS is all-zero (gather target
// for invalid rulebook entries).
__global__ void convert_feats_kernel(const float* __restrict__ feats,
                                     unsigned short* __restrict__ fb) {
  size_t tid  = (size_t)blockIdx.x * blockDim.x + threadIdx.x;
  size_t base = tid * 8;
  const size_t valid_total = (size_t)NPTS * NCH;      // divisible by 8
  const size_t total       = valid_total + NCH;
  if (base >= total) return;
  u16x8 r;
  if (base < valid_total) {
    const float4 a = *reinterpret_cast<const float4*>(feats + base);
    const float4 b = *reinterpret_cast<const float4*>(feats + base + 4);
    r[0] = f2bf(a.x); r[1] = f2bf(a.y); r[2] = f2bf(a.z); r[3] = f2bf(a.w);
    r[4] = f2bf(b.x); r[5] = f2bf(b.y); r[6] = f2bf(b.z); r[7] = f2bf(b.w);
  } else {
    #pragma unroll
    for (int j = 0; j < 8; ++j) r[j] = 0;
  }
  *reinterpret_cast<u16x8*>(fb + base) = r;
}

// weight fp32 [k][cin][cout] -> bf16 lane-major fragment layout:
// element (ko, c, o) -> u16 index (ko*8 + (o>>4)*2 + (c>>5))*512
//                       + (((c>>3)&3)*16 + (o&15))*8 + (c&7)
// so each MFMA B-fragment (ko, nt, half) is one contiguous 1KB block with
// lane L's 16 bytes at L*16. Tiles 27 (pad) are zero.
__global__ void convert_weight_kernel(const float* __restrict__ w,
                                      unsigned short* __restrict__ wt) {
  int tid = blockIdx.x * 256 + threadIdx.x;
  if (tid >= KPAD * NCH * NCH) return;
  int ko  = tid >> 12;        // /4096
  int rem = tid & 4095;
  int c   = rem >> 6;
  int o   = rem & 63;
  unsigned short val = 0;
  if (ko < KOFF) val = f2bf(w[(size_t)ko * 4096 + c * 64 + o]);
  int dst = (ko * 8 + (o >> 4) * 2 + (c >> 5)) * 512
          + (((c >> 3) & 3) * 16 + (o & 15)) * 8 + (c & 7);
  wt[dst] = val;
}

// Main kernel: block = 128 output rows, 4 waves; each wave owns 32 rows
// (2 row-tiles of 16) x all 64 cout. B-fragments are contiguous 1KB wave-loads
// shared by both row-tiles. Depth-2 pipeline (over ko) on the A-gathers.
// MFMA 16x16x32 bf16: A[i][k]: i=lane&15, k=8*(lane>>4)+j; B same k, n=lane&15;
// D[i][n]: n=lane&15, i=4*(lane>>4)+reg.
__global__ __launch_bounds__(256)
void spconv_kernel(const unsigned short* __restrict__ fb,      // (NPTS+1) x 64 bf16
                   const int* __restrict__ rulebook,           // NPTS x 27 int32
                   const unsigned short* __restrict__ wl,      // lane-major weights
                   const float* __restrict__ feats,            // NPTS x 64 fp32
                   const float* __restrict__ bias,             // 64 fp32
                   float* __restrict__ out) {                  // NPTS x 64 fp32
  __shared__ int s_off[128][KPAD];   // BYTE offsets into fb (idx*128)
  __shared__ int s_cnt[128];

  const int tid = threadIdx.x;
  const int m0  = blockIdx.x * 128;

  if (tid < 128) s_cnt[tid] = 0;
  __syncthreads();

  for (int f = tid; f < 128 * KPAD; f += 256) {
    int r = f / KPAD, k = f - r * KPAD;
    int m = m0 + r;
    int off = NPTS * 128;
    if (m < NPTS && k < KOFF) {
      int v = rulebook[(size_t)m * KOFF + k];
      if (v >= 0) { off = v * 128; atomicAdd(&s_cnt[r], 1); }
    }
    s_off[r][k] = off;
  }
  __syncthreads();

  const int wave = tid >> 6;
  const int lane = tid & 63;
  const int lr   = lane & 15;
  const int lk   = lane >> 4;
  const int coff_b = lk * 16;                 // byte offset within 64B half-row
  const int row0 = wave * 32 + lr;            // row-tile 0 A-row
  const int row1 = wave * 32 + 16 + lr;       // row-tile 1 A-row

  const char* fbase = (const char*)fb;

  f32x4 acc0[4] = {f32x4{0,0,0,0}, f32x4{0,0,0,0}, f32x4{0,0,0,0}, f32x4{0,0,0,0}};
  f32x4 acc1[4] = {f32x4{0,0,0,0}, f32x4{0,0,0,0}, f32x4{0,0,0,0}, f32x4{0,0,0,0}};

  // Pipeline stage regs: stage s, row-tile t, cin-half h.
  bf16x8 s0t0h0, s0t0h1, s0t1h0, s0t1h1;
  bf16x8 s1t0h0, s1t0h1, s1t1h0, s1t1h1;

#define GATHER(T0H0, T0H1, T1H0, T1H1, KO) {                                  \
    const char* p0_ = fbase + (size_t)(unsigned)s_off[row0][(KO)];            \
    const char* p1_ = fbase + (size_t)(unsigned)s_off[row1][(KO)];            \
    T0H0 = *reinterpret_cast<const bf16x8*>(p0_ + coff_b);                    \
    T0H1 = *reinterpret_cast<const bf16x8*>(p0_ + 64 + coff_b);               \
    T1H0 = *reinterpret_cast<const bf16x8*>(p1_ + coff_b);                    \
    T1H1 = *reinterpret_cast<const bf16x8*>(p1_ + 64 + coff_b);               \
  }

#define COMPUTE(T0H0, T0H1, T1H0, T1H1, KO) {                                 \
    const unsigned short* wb_ = wl + (size_t)(KO) * 4096 + lane * 8;          \
    _Pragma("unroll")                                                         \
    for (int nt = 0; nt < 4; ++nt) {                                          \
      const bf16x8 b0_ = *reinterpret_cast<const bf16x8*>(wb_ + (nt*2+0)*512);\
      const bf16x8 b1_ = *reinterpret_cast<const bf16x8*>(wb_ + (nt*2+1)*512);\
      acc0[nt] = __builtin_amdgcn_mfma_f32_16x16x32_bf16(T0H0, b0_, acc0[nt],0,0,0);\
      acc0[nt] = __builtin_amdgcn_mfma_f32_16x16x32_bf16(T0H1, b1_, acc0[nt],0,0,0);\
      acc1[nt] = __builtin_amdgcn_mfma_f32_16x16x32_bf16(T1H0, b0_, acc1[nt],0,0,0);\
      acc1[nt] = __builtin_amdgcn_mfma_f32_16x16x32_bf16(T1H1, b1_, acc1[nt],0,0,0);\
    }                                                                         \
  }

  GATHER(s0t0h0, s0t0h1, s0t1h0, s0t1h1, 0)
  GATHER(s1t0h0, s1t0h1, s1t1h0, s1t1h1, 1)

  #pragma unroll 1
  for (int ko = 0; ko < KPAD; ko += 2) {
    COMPUTE(s0t0h0, s0t0h1, s0t1h0, s0t1h1, ko)
    if (ko + 2 < KPAD) GATHER(s0t0h0, s0t0h1, s0t1h0, s0t1h1, ko + 2)
    COMPUTE(s1t0h0, s1t0h1, s1t1h0, s1t1h1, ko + 1)
    if (ko + 3 < KPAD) GATHER(s1t0h0, s1t0h1, s1t1h0, s1t1h1, ko + 3)
  }
#undef GATHER
#undef COMPUTE

  // Epilogue: /denom + bias + residual.
  #pragma unroll
  for (int rt = 0; rt < 2; ++rt) {
    #pragma unroll
    for (int nt = 0; nt < 4; ++nt) {
      const int col = nt * 16 + lr;
      const float b = bias[col];
      #pragma unroll
      for (int i = 0; i < 4; ++i) {
        const int rl = wave * 32 + rt * 16 + lk * 4 + i;
        const int m  = m0 + rl;
        if (m < NPTS) {
          const float denom = (float)max(s_cnt[rl], 1);
          const float a = (rt == 0) ? acc0[nt][i] : acc1[nt][i];
          out[(size_t)m * NCH + col] =
              a / denom + b + feats[(size_t)m * NCH + col];
        }
      }
    }
  }
}

extern "C" void kernel_launch(void* const* d_in, const int* in_sizes, int n_in,
                              void* d_out, int out_size, void* d_ws, size_t ws_size,
                              hipStream_t stream) {
  const float* feats    = (const float*)d_in[0];
  const int*   rulebook = (const int*)d_in[1];
  const float* weight   = (const float*)d_in[2];
  const float* bias     = (const float*)d_in[3];
  float* out = (float*)d_out;

  unsigned short* fb = (unsigned short*)d_ws;
  const size_t fb_bytes = (size_t)(NPTS + 1) * NCH * sizeof(unsigned short);
  const size_t wt_off   = (fb_bytes + 255) & ~(size_t)255;
  unsigned short* wl = (unsigned short*)((char*)d_ws + wt_off);

  {
    const size_t total = (size_t)(NPTS + 1) * NCH;
    const int threads = (int)((total + 7) / 8);
    convert_feats_kernel<<<(threads + 255) / 256, 256, 0, stream>>>(feats, fb);
  }
  {
    const int n = KPAD * NCH * NCH;
    convert_weight_kernel<<<(n + 255) / 256, 256, 0, stream>>>(weight, wl);
  }
  {
    const int nblk = (NPTS + 127) / 128;   // 782
    spconv_kernel<<<nblk, 256, 0, stream>>>(fb, rulebook, wl, feats, bias, out);
  }
}

// Round 4
// 102.280 us; speedup vs baseline: 2.3190x; 1.0760x over previous
//
#include <hip/hip_runtime.h>
#include <hip/hip_bf16.h>

// Problem constants: M=100000 points, K=27 offsets, Cin=Cout=64.
#define NPTS 100000
#define KOFF 27
#define KPAD 28          // padded K: tile 27 = zero weights + zero-row gathers
#define NCH  64
#define CHK  4           // ko per staged LDS chunk
#define NCHUNK (KPAD / CHK)   // 7

typedef __attribute__((ext_vector_type(8))) short bf16x8;   // 8 bf16 in 4 VGPRs
typedef __attribute__((ext_vector_type(8))) unsigned short u16x8;
typedef __attribute__((ext_vector_type(4))) float f32x4;

static __device__ __forceinline__ unsigned short f2bf(float x) {
  union { float f; unsigned int u; } v; v.f = x;
  unsigned int r = v.u + 0x7fffu + ((v.u >> 16) & 1u);   // RTNE
  return (unsigned short)(r >> 16);
}

// feats fp32 (M x 64) -> bf16 (M+1 x 64); row NPTS is all-zero (gather target
// for invalid rulebook entries).
__global__ void convert_feats_kernel(const float* __restrict__ feats,
                                     unsigned short* __restrict__ fb) {
  size_t tid  = (size_t)blockIdx.x * blockDim.x + threadIdx.x;
  size_t base = tid * 8;
  const size_t valid_total = (size_t)NPTS * NCH;
  const size_t total       = valid_total + NCH;
  if (base >= total) return;
  u16x8 r;
  if (base < valid_total) {
    const float4 a = *reinterpret_cast<const float4*>(feats + base);
    const float4 b = *reinterpret_cast<const float4*>(feats + base + 4);
    r[0] = f2bf(a.x); r[1] = f2bf(a.y); r[2] = f2bf(a.z); r[3] = f2bf(a.w);
    r[4] = f2bf(b.x); r[5] = f2bf(b.y); r[6] = f2bf(b.z); r[7] = f2bf(b.w);
  } else {
    #pragma unroll
    for (int j = 0; j < 8; ++j) r[j] = 0;
  }
  *reinterpret_cast<u16x8*>(fb + base) = r;
}

// weight fp32 [k][cin][cout] -> bf16 lane-major fragment layout:
// (ko, c, o) -> u16 index (ko*8 + (o>>4)*2 + (c>>5))*512
//               + (((c>>3)&3)*16 + (o&15))*8 + (c&7)
// Each MFMA B-fragment is one contiguous 1KB block, lane L's 16B at L*16.
__global__ void convert_weight_kernel(const float* __restrict__ w,
                                      unsigned short* __restrict__ wt) {
  int tid = blockIdx.x * 256 + threadIdx.x;
  if (tid >= KPAD * NCH * NCH) return;
  int ko  = tid >> 12;
  int rem = tid & 4095;
  int c   = rem >> 6;
  int o   = rem & 63;
  unsigned short val = 0;
  if (ko < KOFF) val = f2bf(w[(size_t)ko * 4096 + c * 64 + o]);
  int dst = (ko * 8 + (o >> 4) * 2 + (c >> 5)) * 512
          + (((c >> 3) & 3) * 16 + (o & 15)) * 8 + (c & 7);
  wt[dst] = val;
}

// Main kernel: block = 128 rows, 4 waves, wave owns 32 rows (2 row-tiles of 16)
// x 64 cout. Weights staged to LDS in 4-ko chunks (double-buffered, 8 barriers
// per block); B read via ds_read_b128 (lgkmcnt pipe). A-gathers are the only
// in-loop vmem, register-pipelined at distance 4 (16 loads in flight/wave).
__global__ __launch_bounds__(256)
void spconv_kernel(const unsigned short* __restrict__ fb,      // (NPTS+1) x 64 bf16
                   const int* __restrict__ rulebook,           // NPTS x 27 int32
                   const unsigned short* __restrict__ wl,      // lane-major weights
                   const float* __restrict__ feats,            // NPTS x 64 fp32
                   const float* __restrict__ bias,             // 64 fp32
                   float* __restrict__ out) {                  // NPTS x 64 fp32
  __shared__ unsigned short s_b[2][CHK * 4096];   // 2 x 32KB weight chunks
  __shared__ int s_off[128][KPAD];                // BYTE offsets into fb
  __shared__ int s_cnt[128];

  const int tid = threadIdx.x;
  const int m0  = blockIdx.x * 128;

  if (tid < 128) s_cnt[tid] = 0;
  __syncthreads();

  for (int f = tid; f < 128 * KPAD; f += 256) {
    int r = f / KPAD, k = f - r * KPAD;
    int m = m0 + r;
    int off = NPTS * 128;
    if (m < NPTS && k < KOFF) {
      int v = rulebook[(size_t)m * KOFF + k];
      if (v >= 0) { off = v * 128; atomicAdd(&s_cnt[r], 1); }
    }
    s_off[r][k] = off;
  }

  const int wave = tid >> 6;
  const int lane = tid & 63;
  const int lr   = lane & 15;
  const int lk   = lane >> 4;
  const int coff_b = lk * 16;                 // byte offset within 64B half-row
  const int row0 = wave * 32 + lr;
  const int row1 = wave * 32 + 16 + lr;

  const char* fbase = (const char*)fb;
  const char* wlc   = (const char*)wl;

  // Stage chunk: CHK ko = CHK*8KB contiguous; 32 spans of 1KB; wave w takes
  // spans it*4+w, lane L's 16B at L*16 (linear — matches global_load_lds HW).
#define STAGE(C, B) {                                                          \
    const char* gs_ = wlc + (size_t)(C) * (CHK * 8192);                        \
    char* lb_ = (char*)s_b[(B)];                                               \
    _Pragma("unroll")                                                          \
    for (int it = 0; it < 8; ++it) {                                           \
      const int sp_ = it * 4 + wave;                                           \
      __builtin_amdgcn_global_load_lds(                                        \
        (const __attribute__((address_space(1))) unsigned int*)                \
            (gs_ + sp_ * 1024 + lane * 16),                                    \
        (__attribute__((address_space(3))) unsigned int*)                      \
            (lb_ + sp_ * 1024 + lane * 16),                                    \
        16, 0, 0);                                                             \
    }                                                                          \
  }

#define GATHER(T0H0, T0H1, T1H0, T1H1, KO) {                                  \
    const char* p0_ = fbase + (size_t)(unsigned)s_off[row0][(KO)];            \
    const char* p1_ = fbase + (size_t)(unsigned)s_off[row1][(KO)];            \
    T0H0 = *reinterpret_cast<const bf16x8*>(p0_ + coff_b);                    \
    T0H1 = *reinterpret_cast<const bf16x8*>(p0_ + 64 + coff_b);               \
    T1H0 = *reinterpret_cast<const bf16x8*>(p1_ + coff_b);                    \
    T1H1 = *reinterpret_cast<const bf16x8*>(p1_ + 64 + coff_b);               \
  }

#define COMPUTE(T0H0, T0H1, T1H0, T1H1, KL) {                                 \
    _Pragma("unroll")                                                         \
    for (int nt = 0; nt < 4; ++nt) {                                          \
      const bf16x8 b0_ = lb[((KL) * 8 + nt * 2 + 0) * 64 + lane];             \
      const bf16x8 b1_ = lb[((KL) * 8 + nt * 2 + 1) * 64 + lane];             \
      acc0[nt] = __builtin_amdgcn_mfma_f32_16x16x32_bf16(T0H0, b0_, acc0[nt],0,0,0);\
      acc0[nt] = __builtin_amdgcn_mfma_f32_16x16x32_bf16(T0H1, b1_, acc0[nt],0,0,0);\
      acc1[nt] = __builtin_amdgcn_mfma_f32_16x16x32_bf16(T1H0, b0_, acc1[nt],0,0,0);\
      acc1[nt] = __builtin_amdgcn_mfma_f32_16x16x32_bf16(T1H1, b1_, acc1[nt],0,0,0);\
    }                                                                         \
  }

  f32x4 acc0[4] = {f32x4{0,0,0,0}, f32x4{0,0,0,0}, f32x4{0,0,0,0}, f32x4{0,0,0,0}};
  f32x4 acc1[4] = {f32x4{0,0,0,0}, f32x4{0,0,0,0}, f32x4{0,0,0,0}, f32x4{0,0,0,0}};

  // 4 pipeline stage-reg sets (distance-4 over ko).
  bf16x8 A0t0h0, A0t0h1, A0t1h0, A0t1h1;
  bf16x8 A1t0h0, A1t0h1, A1t1h0, A1t1h1;
  bf16x8 A2t0h0, A2t0h1, A2t1h0, A2t1h1;
  bf16x8 A3t0h0, A3t0h1, A3t1h0, A3t1h1;

  STAGE(0, 0)
  __syncthreads();   // s_off visible to all waves; buf0 staged (vmcnt drain)

  GATHER(A0t0h0, A0t0h1, A0t1h0, A0t1h1, 0)
  GATHER(A1t0h0, A1t0h1, A1t1h0, A1t1h1, 1)
  GATHER(A2t0h0, A2t0h1, A2t1h0, A2t1h1, 2)
  GATHER(A3t0h0, A3t0h1, A3t1h0, A3t1h1, 3)

  #pragma unroll 1
  for (int c = 0; c < NCHUNK; ++c) {
    const int b = c & 1;
    if (c + 1 < NCHUNK) STAGE(c + 1, b ^ 1)
    const bf16x8* lb = reinterpret_cast<const bf16x8*>(s_b[b]);
    const int ko = c * CHK;
    COMPUTE(A0t0h0, A0t0h1, A0t1h0, A0t1h1, 0)
    if (ko + 4 < KPAD) GATHER(A0t0h0, A0t0h1, A0t1h0, A0t1h1, ko + 4)
    COMPUTE(A1t0h0, A1t0h1, A1t1h0, A1t1h1, 1)
    if (ko + 5 < KPAD) GATHER(A1t0h0, A1t0h1, A1t1h0, A1t1h1, ko + 5)
    COMPUTE(A2t0h0, A2t0h1, A2t1h0, A2t1h1, 2)
    if (ko + 6 < KPAD) GATHER(A2t0h0, A2t0h1, A2t1h0, A2t1h1, ko + 6)
    COMPUTE(A3t0h0, A3t0h1, A3t1h0, A3t1h1, 3)
    if (ko + 7 < KPAD) GATHER(A3t0h0, A3t0h1, A3t1h0, A3t1h1, ko + 7)
    __syncthreads();   // buf b^1 staged complete; all reads of buf b done
  }
#undef STAGE
#undef GATHER
#undef COMPUTE

  // Epilogue: /denom + bias + residual.
  #pragma unroll
  for (int rt = 0; rt < 2; ++rt) {
    #pragma unroll
    for (int nt = 0; nt < 4; ++nt) {
      const int col = nt * 16 + lr;
      const float b = bias[col];
      #pragma unroll
      for (int i = 0; i < 4; ++i) {
        const int rl = wave * 32 + rt * 16 + lk * 4 + i;
        const int m  = m0 + rl;
        if (m < NPTS) {
          const float denom = (float)max(s_cnt[rl], 1);
          const float a = (rt == 0) ? acc0[nt][i] : acc1[nt][i];
          out[(size_t)m * NCH + col] =
              a / denom + b + feats[(size_t)m * NCH + col];
        }
      }
    }
  }
}

extern "C" void kernel_launch(void* const* d_in, const int* in_sizes, int n_in,
                              void* d_out, int out_size, void* d_ws, size_t ws_size,
                              hipStream_t stream) {
  const float* feats    = (const float*)d_in[0];
  const int*   rulebook = (const int*)d_in[1];
  const float* weight   = (const float*)d_in[2];
  const float* bias     = (const float*)d_in[3];
  float* out = (float*)d_out;

  unsigned short* fb = (unsigned short*)d_ws;
  const size_t fb_bytes = (size_t)(NPTS + 1) * NCH * sizeof(unsigned short);
  const size_t wt_off   = (fb_bytes + 255) & ~(size_t)255;
  unsigned short* wl = (unsigned short*)((char*)d_ws + wt_off);

  {
    const size_t total = (size_t)(NPTS + 1) * NCH;
    const int threads = (int)((total + 7) / 8);
    convert_feats_kernel<<<(threads + 255) / 256, 256, 0, stream>>>(feats, fb);
  }
  {
    const int n = KPAD * NCH * NCH;
    convert_weight_kernel<<<(n + 255) / 256, 256, 0, stream>>>(weight, wl);
  }
  {
    const int nblk = (NPTS + 127) / 128;   // 782
    spconv_kernel<<<nblk, 256, 0, stream>>>(fb, rulebook, wl, feats, bias, out);
  }
}